// Round 6
// baseline (105.621 us; speedup 1.0000x reference)
//
#include <hip/hip_runtime.h>
#include <math.h>

// One WAVE per walker, block = 256 = 4 independent walkers. No LDS, no barriers.
// Register-pressure-first design: h is NEVER held across phases.
//   dot:  2 streaming passes over h (one per k-half), 32 accumulators + 32 W regs
//   det:  a[7][7] (49 regs) live only after accumulators die -> no AGPR spill
//   store: 3rd read of h (L2/L3-hot, independent of det chain), fully coalesced.

__global__ __launch_bounds__(256, 5)
void orbital_cof_kernel(const float* __restrict__ h_g,   // (B,16,256)
                        const float* __restrict__ r_g,   // (B,16,4,3)
                        const float* __restrict__ W_g,   // (2,256,8)
                        const float* __restrict__ b_g,   // (2,8)
                        const float* __restrict__ dec_g, // (2,4,8)
                        const float* __restrict__ pi_g,  // (2,4,8)
                        float* __restrict__ out,         // (2,B,8,256)
                        int nb)
{
    const int t = threadIdx.x;
    const int wave = t >> 6;
    const int lane = t & 63;
    const int b = blockIdx.x * 4 + wave;
    if (b >= nb) return;                 // no barriers anywhere: safe

    const int s  = lane >> 5;            // spin (half-wave each)
    const int hl = lane & 31;            // lane within spin half

    // ---- distance held by this lane: lane = s*32 + n*4 + i (matches r layout) ----
    float dist;
    {
        const float* rp = r_g + (size_t)b * 192 + lane * 3;
        float x = rp[0], y = rp[1], z = rp[2];
        dist = sqrtf(x * x + y * y + z * z);
    }

    const float* hb = h_g + (size_t)b * 4096 + s * 2048 + hl * 8;

    // ---- dot: lane owns d in [hl*8, hl*8+8); stream h per k-half (unroll 1
    //      keeps the two passes' loads separate -> h never held in regs) ----
    float mA = 0.f, mB = 0.f;
#pragma unroll 1
    for (int kh = 0; kh < 2; ++kh) {
        float wv[8][4];                  // W[s][hl*8+dd][kh*4+kk], L1/L2-hot
        const float* wp = W_g + s * 2048 + hl * 64 + kh * 4;
#pragma unroll
        for (int dd = 0; dd < 8; ++dd) {
            float4 w = *(const float4*)(wp + dd * 8);
            wv[dd][0] = w.x; wv[dd][1] = w.y; wv[dd][2] = w.z; wv[dd][3] = w.w;
        }
        float v[32];
#pragma unroll
        for (int n = 0; n < 8; ++n) {
            float4 h0 = *(const float4*)(hb + n * 256);
            float4 h1 = *(const float4*)(hb + n * 256 + 4);
#pragma unroll
            for (int kk = 0; kk < 4; ++kk) {
                float acc = h0.x * wv[0][kk];
                acc = fmaf(h0.y, wv[1][kk], acc);
                acc = fmaf(h0.z, wv[2][kk], acc);
                acc = fmaf(h0.w, wv[3][kk], acc);
                acc = fmaf(h1.x, wv[4][kk], acc);
                acc = fmaf(h1.y, wv[5][kk], acc);
                acc = fmaf(h1.z, wv[6][kk], acc);
                acc = fmaf(h1.w, wv[7][kk], acc);
                v[n * 4 + kk] = acc;
            }
        }
        // halving butterfly within the 32-lane half: lane hl ends with entry hl
#pragma unroll
        for (int i = 0; i < 16; ++i) {
            float send = (hl & 16) ? v[i] : v[i + 16];
            float recv = __shfl_xor(send, 16);
            v[i] = ((hl & 16) ? v[i + 16] : v[i]) + recv;
        }
#pragma unroll
        for (int i = 0; i < 8; ++i) {
            float send = (hl & 8) ? v[i] : v[i + 8];
            float recv = __shfl_xor(send, 8);
            v[i] = ((hl & 8) ? v[i + 8] : v[i]) + recv;
        }
#pragma unroll
        for (int i = 0; i < 4; ++i) {
            float send = (hl & 4) ? v[i] : v[i + 4];
            float recv = __shfl_xor(send, 4);
            v[i] = ((hl & 4) ? v[i + 4] : v[i]) + recv;
        }
#pragma unroll
        for (int i = 0; i < 2; ++i) {
            float send = (hl & 2) ? v[i] : v[i + 2];
            float recv = __shfl_xor(send, 2);
            v[i] = ((hl & 2) ? v[i + 2] : v[i]) + recv;
        }
        {
            float send = (hl & 1) ? v[0] : v[1];
            float recv = __shfl_xor(send, 1);
            v[0] = ((hl & 1) ? v[1] : v[0]) + recv;
        }
        if (kh == 0) mA = v[0]; else mB = v[0];
    }

    // ---- env + bias on this lane's two M entries (lane hl = n*4 + kl) ----
    {
        const int nm = hl >> 2;
        const int kl = hl & 3;
        float dn[4];
#pragma unroll
        for (int i = 0; i < 4; ++i)
            dn[i] = __shfl(dist, s * 32 + nm * 4 + i);
        const int kA = kl, kB = kl + 4;
        float envA = 0.f, envB = 0.f;
#pragma unroll
        for (int i = 0; i < 4; ++i) {
            envA = fmaf(pi_g[s * 32 + i * 8 + kA], __expf(-dn[i] * dec_g[s * 32 + i * 8 + kA]), envA);
            envB = fmaf(pi_g[s * 32 + i * 8 + kB], __expf(-dn[i] * dec_g[s * 32 + i * 8 + kB]), envB);
        }
        mA = (mA + b_g[s * 8 + kA]) * envA;
        mB = (mB + b_g[s * 8 + kB]) * envB;
    }

    // ---- gather 7x7 minor for det-lane nd = hl&7 (M[s][n][k] lives at lane
    //      s*32 + n*4 + (k&3): mA for k<4, mB for k>=4) ----
    const int nd = hl & 7;
    const int base = s * 32;
    float a[7][7];
#pragma unroll
    for (int i = 0; i < 7; ++i) {
        int src = i + (i >= nd ? 1 : 0);          // skip row nd
#pragma unroll
        for (int j = 0; j < 7; ++j) {
            const int k = j + 1;                  // skip col 0
            int sl = base + src * 4 + (k & 3);
            a[i][j] = (k < 4) ? __shfl(mA, sl) : __shfl(mB, sl);
        }
    }
    float m0 = __shfl(mA, base + nd * 4);         // M[s][nd][0]

    // ---- 16 serial pivoted 7x7 dets (lanes hl<8 of each half) ----
    float anti = 0.f;
    if (hl < 8) {
        float det = 1.f;
#pragma unroll
        for (int kk = 0; kk < 7; ++kk) {
#pragma unroll
            for (int i = kk + 1; i < 7; ++i) {
                bool sw = fabsf(a[i][kk]) > fabsf(a[kk][kk]);
#pragma unroll
                for (int j = kk; j < 7; ++j) {
                    float tk = a[kk][j], ti = a[i][j];
                    a[kk][j] = sw ? ti : tk;
                    a[i][j]  = sw ? tk : ti;
                }
                det = sw ? -det : det;
            }
            float piv = a[kk][kk];
            det *= piv;
            float rp = (piv != 0.f) ? (1.f / piv) : 0.f;
#pragma unroll
            for (int i = kk + 1; i < 7; ++i) {
                float f = a[i][kk] * rp;
#pragma unroll
                for (int j = kk + 1; j < 7; ++j) a[i][j] = fmaf(-f, a[kk][j], a[i][j]);
            }
        }
        anti = m0 * ((nd & 1) ? -1.f : 1.f) * det;
    }

    // ---- store: re-read h (L2/L3-hot, independent of det -> can hoist),
    //      full-64-lane rows: one 1KB perfectly-coalesced float4 instr per row ----
    {
        const float* hb2 = h_g + (size_t)b * 4096 + lane * 4;
#pragma unroll
        for (int row = 0; row < 16; ++row) {
            int s2 = row >> 3;
            int n2 = row & 7;
            float an = __shfl(anti, s2 * 32 + n2);
            float4 hx = *(const float4*)(hb2 + row * 256);
            float4 o = make_float4(hx.x * an, hx.y * an, hx.z * an, hx.w * an);
            float* op = out + (size_t)s2 * (size_t)nb * 2048 + (size_t)b * 2048
                          + n2 * 256 + lane * 4;
            *(float4*)op = o;
        }
    }
}

extern "C" void kernel_launch(void* const* d_in, const int* in_sizes, int n_in,
                              void* d_out, int out_size, void* d_ws, size_t ws_size,
                              hipStream_t stream) {
    int nb = in_sizes[0] / 4096;      // B = elems / (S*N*D)
    const float* h_g   = (const float*)d_in[0];
    const float* r_g   = (const float*)d_in[1];
    const float* W_g   = (const float*)d_in[2];
    const float* b_g   = (const float*)d_in[3];
    const float* dec_g = (const float*)d_in[4];
    const float* pi_g  = (const float*)d_in[5];
    int grid = (nb + 3) / 4;
    orbital_cof_kernel<<<dim3(grid), dim3(256), 0, stream>>>(
        h_g, r_g, W_g, b_g, dec_g, pi_g, (float*)d_out, nb);
}

// Round 7
// 58.156 us; speedup vs baseline: 1.8162x; 1.8162x over previous
//
#include <hip/hip_runtime.h>
#include <math.h>

// One 256-thread block per walker. S=2, N=8, D=256, I=4.
// r3 structure (best: h staged once to LDS, register-W dot, butterfly reduce)
// with the det phase replaced: no-pivot Gaussian elimination (chain ~250 cyc
// vs ~2100 for bubble-pivoted) + min|pivot| tracking + rare pivoted fallback.

__global__ __launch_bounds__(256, 4)
void orbital_cof_kernel(const float* __restrict__ h_g,   // (B,16,256)
                        const float* __restrict__ r_g,   // (B,16,4,3)
                        const float* __restrict__ W_g,   // (2,256,8)
                        const float* __restrict__ b_g,   // (2,8)
                        const float* __restrict__ dec_g, // (2,4,8)
                        const float* __restrict__ pi_g,  // (2,4,8)
                        float* __restrict__ out,         // (2,B,8,256)
                        int nb)
{
    __shared__ float hs[16][264];    // 16.9 KB, rows 16B-aligned
    __shared__ float Ms[2][8][8];
    __shared__ float anti_s[16];
    __shared__ float dist_s[64];     // [s*32 + n*4 + i]

    const int t = threadIdx.x;
    const int b = blockIdx.x;
    const int wave = t >> 6;         // 0..3
    const int lane = t & 63;
    const int s  = wave >> 1;        // spin
    const int kh = wave & 1;         // k half

    // ---- W into registers: lane covers d0=4*lane..+4, k=kh*4..+4 ----
    float wv[4][4];
    {
        const float* wp = W_g + s * 2048 + lane * 32 + kh * 4;
#pragma unroll
        for (int dd = 0; dd < 4; ++dd) {
            float4 w = *(const float4*)(wp + dd * 8);
            wv[dd][0] = w.x; wv[dd][1] = w.y; wv[dd][2] = w.z; wv[dd][3] = w.w;
        }
    }

    // ---- stage h (coalesced float4) ----
    const float4* h4p = (const float4*)(h_g + (size_t)b * 4096);
#pragma unroll
    for (int it = 0; it < 4; ++it) {
        int f4 = t + it * 256;
        int row = f4 >> 6;           // s*8+n
        int d4 = (f4 & 63) << 2;
        float4 v = h4p[f4];
        *(float4*)&hs[row][d4] = v;
    }

    // ---- distances (t<64): t = s*32 + n*4 + i matches r layout ----
    if (t < 64) {
        const float* rp = r_g + (size_t)b * 192 + t * 3;
        float x = rp[0], y = rp[1], z = rp[2];
        dist_s[t] = sqrtf(x * x + y * y + z * z);
    }
    __syncthreads();

    // ---- dot: p[n*4+kl] = sum over lane's 4 d of h[n][d]*W[d][k] ----
    float v[32];
#pragma unroll
    for (int n = 0; n < 8; ++n) {
        float4 hv = *(const float4*)&hs[s * 8 + n][lane * 4];
#pragma unroll
        for (int kl = 0; kl < 4; ++kl) {
            float acc;
            acc = hv.x * wv[0][kl];
            acc = fmaf(hv.y, wv[1][kl], acc);
            acc = fmaf(hv.z, wv[2][kl], acc);
            acc = fmaf(hv.w, wv[3][kl], acc);
            v[n * 4 + kl] = acc;
        }
    }

    // ---- halving-butterfly reduce over 64 lanes ----
#pragma unroll
    for (int i = 0; i < 16; ++i) {
        float send = (lane & 32) ? v[i] : v[i + 16];
        float recv = __shfl_xor(send, 32);
        v[i] = ((lane & 32) ? v[i + 16] : v[i]) + recv;
    }
#pragma unroll
    for (int i = 0; i < 8; ++i) {
        float send = (lane & 16) ? v[i] : v[i + 8];
        float recv = __shfl_xor(send, 16);
        v[i] = ((lane & 16) ? v[i + 8] : v[i]) + recv;
    }
#pragma unroll
    for (int i = 0; i < 4; ++i) {
        float send = (lane & 8) ? v[i] : v[i + 4];
        float recv = __shfl_xor(send, 8);
        v[i] = ((lane & 8) ? v[i + 4] : v[i]) + recv;
    }
#pragma unroll
    for (int i = 0; i < 2; ++i) {
        float send = (lane & 4) ? v[i] : v[i + 2];
        float recv = __shfl_xor(send, 4);
        v[i] = ((lane & 4) ? v[i + 2] : v[i]) + recv;
    }
    {
        float send = (lane & 2) ? v[0] : v[1];
        float recv = __shfl_xor(send, 2);
        v[0] = ((lane & 2) ? v[1] : v[0]) + recv;
    }
    float tot = v[0] + __shfl_xor(v[0], 1);

    // ---- env + bias -> Ms (even lanes hold (n,k) = lane>>1) ----
    if ((lane & 1) == 0) {
        int idx = lane >> 1;         // n*4 + kl
        int n = idx >> 2;
        int k = kh * 4 + (idx & 3);
        float lin = tot + b_g[s * 8 + k];
        float env = 0.f;
#pragma unroll
        for (int i = 0; i < 4; ++i) {
            float dd = dist_s[s * 32 + n * 4 + i];
            env = fmaf(pi_g[s * 32 + i * 8 + k], __expf(-dd * dec_g[s * 32 + i * 8 + k]), env);
        }
        Ms[s][n][k] = lin * env;
    }
    __syncthreads();

    // ---- 16 cofactor determinants (7x7): fast no-pivot GE with pivoted fallback ----
    if (t < 16) {
        int ss = t >> 3;
        int n = t & 7;
        float a[7][7];
        float sc = 0.f;
#pragma unroll
        for (int i = 0; i < 7; ++i) {
            int src = i + (i >= n);  // skip row n
#pragma unroll
            for (int j = 0; j < 7; ++j) {
                float x = Ms[ss][src][j + 1];   // skip col 0
                a[i][j] = x;
                sc = fmaxf(sc, fabsf(x));
            }
        }
        // fast path: Gaussian elimination, no pivoting (short dependency chain)
        float det = 1.f;
        float minp = 3.4e38f;
#pragma unroll
        for (int kk = 0; kk < 7; ++kk) {
            float piv = a[kk][kk];
            minp = fminf(minp, fabsf(piv));
            det *= piv;
            float rp = 1.f / piv;
#pragma unroll
            for (int i = kk + 1; i < 7; ++i) {
                float f = a[i][kk] * rp;
#pragma unroll
                for (int j = kk + 1; j < 7; ++j) a[i][j] = fmaf(-f, a[kk][j], a[i][j]);
            }
        }
        // fallback: rare (small pivot relative to matrix scale, or zero/NaN)
        if (!(minp > 1e-3f * sc)) {
#pragma unroll
            for (int i = 0; i < 7; ++i) {
                int src = i + (i >= n);
#pragma unroll
                for (int j = 0; j < 7; ++j) a[i][j] = Ms[ss][src][j + 1];
            }
            det = 1.f;
#pragma unroll
            for (int kk = 0; kk < 7; ++kk) {
#pragma unroll
                for (int i = kk + 1; i < 7; ++i) {
                    bool sw = fabsf(a[i][kk]) > fabsf(a[kk][kk]);
#pragma unroll
                    for (int j = kk; j < 7; ++j) {
                        float tk = a[kk][j], ti = a[i][j];
                        a[kk][j] = sw ? ti : tk;
                        a[i][j]  = sw ? tk : ti;
                    }
                    det = sw ? -det : det;
                }
                float piv = a[kk][kk];
                det *= piv;
                float rp = (piv != 0.f) ? (1.f / piv) : 0.f;
#pragma unroll
                for (int i = kk + 1; i < 7; ++i) {
                    float f = a[i][kk] * rp;
#pragma unroll
                    for (int j = kk + 1; j < 7; ++j) a[i][j] = fmaf(-f, a[kk][j], a[i][j]);
                }
            }
        }
        float sgn = (n & 1) ? -1.f : 1.f;
        anti_s[t] = Ms[ss][n][0] * sgn * det;
    }
    __syncthreads();

    // ---- out = h * anti; coalesced float4 stores; tuple layout (s=0, s=1) ----
#pragma unroll
    for (int it = 0; it < 4; ++it) {
        int f4 = t + it * 256;
        int row = f4 >> 6;           // s*8+n
        int d4 = (f4 & 63) << 2;
        float4 hv = *(const float4*)&hs[row][d4];
        float aa = anti_s[row];
        float4 o = make_float4(hv.x * aa, hv.y * aa, hv.z * aa, hv.w * aa);
        int so = row >> 3;
        int n = row & 7;
        size_t off = (size_t)so * (size_t)nb * 2048 + (size_t)b * 2048 + (size_t)(n * 256 + d4);
        *(float4*)(out + off) = o;
    }
}

extern "C" void kernel_launch(void* const* d_in, const int* in_sizes, int n_in,
                              void* d_out, int out_size, void* d_ws, size_t ws_size,
                              hipStream_t stream) {
    int nb = in_sizes[0] / 4096;     // B = elems / (S*N*D)
    const float* h_g   = (const float*)d_in[0];
    const float* r_g   = (const float*)d_in[1];
    const float* W_g   = (const float*)d_in[2];
    const float* b_g   = (const float*)d_in[3];
    const float* dec_g = (const float*)d_in[4];
    const float* pi_g  = (const float*)d_in[5];
    orbital_cof_kernel<<<dim3(nb), dim3(256), 0, stream>>>(
        h_g, r_g, W_g, b_g, dec_g, pi_g, (float*)d_out, nb);
}

// Round 8
// 56.217 us; speedup vs baseline: 1.8788x; 1.0345x over previous
//
#include <hip/hip_runtime.h>
#include <math.h>

// One 256-thread block per walker. S=2, N=8, D=256, I=4.
// r3 structure with LDS trimmed to 16.4 KB (stride-256 hs: every access here
// has row fixed per wave-instruction, so padding was never needed) -> 8
// resident blocks/CU (32-wave cap). Pivoted serial det (best measured).

__global__ __launch_bounds__(256, 8)
void orbital_cof_kernel(const float* __restrict__ h_g,   // (B,16,256)
                        const float* __restrict__ r_g,   // (B,16,4,3)
                        const float* __restrict__ W_g,   // (2,256,8)
                        const float* __restrict__ b_g,   // (2,8)
                        const float* __restrict__ dec_g, // (2,4,8)
                        const float* __restrict__ pi_g,  // (2,4,8)
                        float* __restrict__ out,         // (2,B,8,256)
                        int nb)
{
    __shared__ float hs[16][256];    // 16 KB flat copy of this walker's h
    __shared__ float Ms[2][8][8];
    __shared__ float anti_s[16];
    __shared__ float dist_s[64];     // [s*32 + n*4 + i]

    const int t = threadIdx.x;
    const int b = blockIdx.x;
    const int wave = t >> 6;         // 0..3
    const int lane = t & 63;
    const int s  = wave >> 1;        // spin
    const int kh = wave & 1;         // k half

    // ---- W into registers: lane covers d0=4*lane..+4, k=kh*4..+4 ----
    float wv[4][4];
    {
        const float* wp = W_g + s * 2048 + lane * 32 + kh * 4;
#pragma unroll
        for (int dd = 0; dd < 4; ++dd) {
            float4 w = *(const float4*)(wp + dd * 8);
            wv[dd][0] = w.x; wv[dd][1] = w.y; wv[dd][2] = w.z; wv[dd][3] = w.w;
        }
    }

    // ---- stage h: flat coalesced float4 copy ----
    const float4* h4p = (const float4*)(h_g + (size_t)b * 4096);
    float4* hs4 = (float4*)hs;
#pragma unroll
    for (int it = 0; it < 4; ++it)
        hs4[t + it * 256] = h4p[t + it * 256];

    // ---- distances (t<64): t = s*32 + n*4 + i matches r layout ----
    if (t < 64) {
        const float* rp = r_g + (size_t)b * 192 + t * 3;
        float x = rp[0], y = rp[1], z = rp[2];
        dist_s[t] = sqrtf(x * x + y * y + z * z);
    }
    __syncthreads();

    // ---- dot: p[n*4+kl] = sum over lane's 4 d of h[n][d]*W[d][k] ----
    float v[32];
#pragma unroll
    for (int n = 0; n < 8; ++n) {
        float4 hv = *(const float4*)&hs[s * 8 + n][lane * 4];
#pragma unroll
        for (int kl = 0; kl < 4; ++kl) {
            float acc;
            acc = hv.x * wv[0][kl];
            acc = fmaf(hv.y, wv[1][kl], acc);
            acc = fmaf(hv.z, wv[2][kl], acc);
            acc = fmaf(hv.w, wv[3][kl], acc);
            v[n * 4 + kl] = acc;
        }
    }

    // ---- halving-butterfly reduce over 64 lanes ----
#pragma unroll
    for (int i = 0; i < 16; ++i) {
        float send = (lane & 32) ? v[i] : v[i + 16];
        float recv = __shfl_xor(send, 32);
        v[i] = ((lane & 32) ? v[i + 16] : v[i]) + recv;
    }
#pragma unroll
    for (int i = 0; i < 8; ++i) {
        float send = (lane & 16) ? v[i] : v[i + 8];
        float recv = __shfl_xor(send, 16);
        v[i] = ((lane & 16) ? v[i + 8] : v[i]) + recv;
    }
#pragma unroll
    for (int i = 0; i < 4; ++i) {
        float send = (lane & 8) ? v[i] : v[i + 4];
        float recv = __shfl_xor(send, 8);
        v[i] = ((lane & 8) ? v[i + 4] : v[i]) + recv;
    }
#pragma unroll
    for (int i = 0; i < 2; ++i) {
        float send = (lane & 4) ? v[i] : v[i + 2];
        float recv = __shfl_xor(send, 4);
        v[i] = ((lane & 4) ? v[i + 2] : v[i]) + recv;
    }
    {
        float send = (lane & 2) ? v[0] : v[1];
        float recv = __shfl_xor(send, 2);
        v[0] = ((lane & 2) ? v[1] : v[0]) + recv;
    }
    float tot = v[0] + __shfl_xor(v[0], 1);

    // ---- env + bias -> Ms (even lanes hold (n,k) = lane>>1) ----
    if ((lane & 1) == 0) {
        int idx = lane >> 1;         // n*4 + kl
        int n = idx >> 2;
        int k = kh * 4 + (idx & 3);
        float lin = tot + b_g[s * 8 + k];
        float env = 0.f;
#pragma unroll
        for (int i = 0; i < 4; ++i) {
            float dd = dist_s[s * 32 + n * 4 + i];
            env = fmaf(pi_g[s * 32 + i * 8 + k], __expf(-dd * dec_g[s * 32 + i * 8 + k]), env);
        }
        Ms[s][n][k] = lin * env;
    }
    __syncthreads();

    // ---- 16 cofactor determinants (7x7, partial pivoting, reg-resident) ----
    if (t < 16) {
        int ss = t >> 3;
        int n = t & 7;
        float a[7][7];
#pragma unroll
        for (int i = 0; i < 7; ++i) {
            int src = i + (i >= n);  // skip row n
#pragma unroll
            for (int j = 0; j < 7; ++j) a[i][j] = Ms[ss][src][j + 1];  // skip col 0
        }
        float det = 1.f;
#pragma unroll
        for (int kk = 0; kk < 7; ++kk) {
#pragma unroll
            for (int i = kk + 1; i < 7; ++i) {
                bool sw = fabsf(a[i][kk]) > fabsf(a[kk][kk]);
#pragma unroll
                for (int j = kk; j < 7; ++j) {
                    float tk = a[kk][j], ti = a[i][j];
                    a[kk][j] = sw ? ti : tk;
                    a[i][j]  = sw ? tk : ti;
                }
                det = sw ? -det : det;
            }
            float piv = a[kk][kk];
            det *= piv;
            float rp = (piv != 0.f) ? (1.f / piv) : 0.f;
#pragma unroll
            for (int i = kk + 1; i < 7; ++i) {
                float f = a[i][kk] * rp;
#pragma unroll
                for (int j = kk + 1; j < 7; ++j) a[i][j] = fmaf(-f, a[kk][j], a[i][j]);
            }
        }
        float sgn = (n & 1) ? -1.f : 1.f;
        anti_s[t] = Ms[ss][n][0] * sgn * det;
    }
    __syncthreads();

    // ---- out = h * anti; coalesced float4 stores; tuple layout (s=0, s=1) ----
#pragma unroll
    for (int it = 0; it < 4; ++it) {
        int f4 = t + it * 256;
        int row = f4 >> 6;           // s*8+n
        int d4 = (f4 & 63) << 2;
        float4 hv = *(const float4*)&hs[row][d4];
        float aa = anti_s[row];
        float4 o = make_float4(hv.x * aa, hv.y * aa, hv.z * aa, hv.w * aa);
        int so = row >> 3;
        int n = row & 7;
        size_t off = (size_t)so * (size_t)nb * 2048 + (size_t)b * 2048 + (size_t)(n * 256 + d4);
        *(float4*)(out + off) = o;
    }
}

extern "C" void kernel_launch(void* const* d_in, const int* in_sizes, int n_in,
                              void* d_out, int out_size, void* d_ws, size_t ws_size,
                              hipStream_t stream) {
    int nb = in_sizes[0] / 4096;     // B = elems / (S*N*D)
    const float* h_g   = (const float*)d_in[0];
    const float* r_g   = (const float*)d_in[1];
    const float* W_g   = (const float*)d_in[2];
    const float* b_g   = (const float*)d_in[3];
    const float* dec_g = (const float*)d_in[4];
    const float* pi_g  = (const float*)d_in[5];
    orbital_cof_kernel<<<dim3(nb), dim3(256), 0, stream>>>(
        h_g, r_g, W_g, b_g, dec_g, pi_g, (float*)d_out, nb);
}